// Round 11
// baseline (96.122 us; speedup 1.0000x reference)
//
#include <hip/hip_runtime.h>
#include <math.h>

// Problem constants: B=32, F=2048, hw=49, A=1.
#define BB    32
#define FF    2048
#define HW    49
#define ROWS  (BB * FF)
#define DPAD  64
#define SPLIT 4
#define GSTEP 64
#define GHALF (FF / SPLIT)               // 512
#define NSTEP (GHALF / GSTEP)            // 8

typedef float f32x16 __attribute__((ext_vector_type(16)));
typedef _Float16 f16x8 __attribute__((ext_vector_type(8)));
typedef short s16x8 __attribute__((ext_vector_type(8)));

// exp2 via the amdgcn builtin -> single v_exp_f32, compiler-managed hazards.
__device__ inline float exp2_fast(float x) {
    return __builtin_amdgcn_exp2f(x);
}

// fp32 -> fp16 hi + fp16 lo (RNE), packed (hi<<16)|lo. Combined rel err ~2^-22.
__device__ inline unsigned f16pack(float v) {
    _Float16 h = (_Float16)v;
    _Float16 l = (_Float16)(v - (float)h);
    unsigned hb = (unsigned)__builtin_bit_cast(unsigned short, h);
    unsigned lb = (unsigned)__builtin_bit_cast(unsigned short, l);
    return (hb << 16) | lb;
}

__device__ inline void unpack8(uint4 a, uint4 b, f16x8& h, f16x8& l) {
    unsigned w[8] = {a.x, a.y, a.z, a.w, b.x, b.y, b.z, b.w};
    s16x8 hs, ls;
    #pragma unroll
    for (int i = 0; i < 8; ++i) {
        hs[i] = (short)(w[i] >> 16);
        ls[i] = (short)(w[i] & 0xFFFFu);
    }
    h = __builtin_bit_cast(f16x8, hs);
    l = __builtin_bit_cast(f16x8, ls);
}

// Build B-operand frags (y for this lane's f-col) from the per-lane y regs
// after the cross-half exchange. pk[j=dt*16+r] = y[f][dt*32+(r&3)+8*(r>>2)+4H],
// ot[j] = partner half's pk[j]. All indices compile-time (H is a template arg).
template<int H>
__device__ inline void build_frags(const unsigned pk[32], const unsigned ot[32],
                                   f16x8 qhf[4], f16x8 qlf[4]) {
    #pragma unroll
    for (int ks = 0; ks < 4; ++ks) {
        s16x8 hs, ls;
        #pragma unroll
        for (int i = 0; i < 8; ++i) {
            const int d    = ks * 16 + H * 8 + i;
            const int dt   = d >> 5;
            const int d5   = d & 31;
            const int hsrc = (d5 >> 2) & 1;
            const int r    = ((d5 >> 3) << 2) | (d5 & 3);
            const int j    = dt * 16 + r;
            const unsigned v = (hsrc == H) ? pk[j] : ot[j];
            hs[i] = (short)(v >> 16);
            ls[i] = (short)(v & 0xFFFFu);
        }
        qhf[ks] = __builtin_bit_cast(f16x8, hs);
        qlf[ks] = __builtin_bit_cast(f16x8, ls);
    }
}

// ---------------------------------------------------------------------------
// prep: M[j,d] = sum_e Wq[e,j] Wk[e,d] * log2(e)/7 -> Mtpk[d][j] (fp16 hi/lo)
//       u[d]   = sum_e Wv[e,d] * Wout[e]
// ---------------------------------------------------------------------------
__global__ __launch_bounds__(256) void prep_kernel(
    const float* __restrict__ Wqkv, const float* __restrict__ Wout,
    unsigned* __restrict__ Mtpk, float* __restrict__ u)
{
    __shared__ float W2[98][52];
    const int tid = threadIdx.x;
    if (blockIdx.x < 16) {
        for (int i = tid; i < 98 * 52; i += 256) {
            int e = i / 52, j = i - e * 52;
            W2[e][j] = (j < HW) ? Wqkv[e * HW + j] : 0.f;
        }
        __syncthreads();
        const int d = blockIdx.x * 4 + (tid >> 6);
        const int j = tid & 63;
        float s = 0.f;
        if (d < HW && j < HW) {
            for (int e = 0; e < HW; ++e) s = fmaf(W2[e][j], W2[49 + e][d], s);
            s *= 0.2060992915555662f;      // log2(e) / 7
        }
        Mtpk[d * 64 + j] = f16pack(s);
    } else {
        if (tid < 64) {
            float s = 0.f;
            if (tid < HW)
                for (int e = 0; e < HW; ++e)
                    s = fmaf(Wqkv[(98 + e) * HW + tid], Wout[e], s);
            u[tid] = s;
        }
    }
}

// ---------------------------------------------------------------------------
// xconv: x fp32 -> fp16 hi/lo panels xh/xl [row][64] + wv = x.u.
// XCD-affinity swizzle: XCD k produces b in [4k,4k+4) (what its attn reads).
// ---------------------------------------------------------------------------
__global__ __launch_bounds__(256) void xconv_kernel(
    const float* __restrict__ x, const float* __restrict__ u,
    unsigned short* __restrict__ xh, unsigned short* __restrict__ xl,
    float* __restrict__ wv)
{
    __shared__ float xsh[128 * HW];
    __shared__ float ush[64];
    const int blk = (blockIdx.x & 7) * 64 + (blockIdx.x >> 3);   // affinity map
    const int tid = threadIdx.x, lane = tid & 63, wid = tid >> 6;
    const int col = lane & 31, half = lane >> 5;
    if (tid < 64) ush[tid] = u[tid];

    {
        const float* xb = x + (size_t)blk * 128 * HW;
        for (int i = tid; i < 128 * HW; i += 256) xsh[i] = xb[i];
    }
    __syncthreads();

    const int rloc = wid * 32 + col;
    const int row = blk * 128 + rloc;

    float wp = 0.f;
    #pragma unroll
    for (int ks = 0; ks < 4; ++ks) {
        s16x8 hs, ls;
        #pragma unroll
        for (int i = 0; i < 8; ++i) {
            int d = ks * 16 + half * 8 + i;
            float t = (d < HW) ? xsh[rloc * HW + d] : 0.f;
            wp = fmaf(t, ush[d], wp);
            _Float16 h = (_Float16)t;
            _Float16 l = (_Float16)(t - (float)h);
            hs[i] = __builtin_bit_cast(short, h);
            ls[i] = __builtin_bit_cast(short, l);
        }
        const size_t o = (size_t)row * DPAD + ks * 16 + half * 8;
        *(f16x8*)(xh + o) = __builtin_bit_cast(f16x8, hs);
        *(f16x8*)(xl + o) = __builtin_bit_cast(f16x8, ls);
    }
    wp += __shfl_xor(wp, 32);
    if (half == 0) wv[row] = wp;
}

// ---------------------------------------------------------------------------
// attn: per block, PROLOGUE computes y = x.M for its 32 f-cols via MFMA
// (A = Mt-row frags, B = x-row frags -> lane n = f, regs = d), cross-half
// shfl exchange builds B-operand y frags in hi/lo fp16. MAIN LOOP (proven
// round-10 structure): scores(log2) = y . xh^T, 2 MFMAs per ks, no-max
// softmax via v_exp_f32, scalar value w. K-tile 64 rows double-buffered.
// All panel traffic is local-L2 (xconv affinity); no ypk panel exists.
// ---------------------------------------------------------------------------
__global__ __launch_bounds__(256, 4) void attn_kernel(
    const unsigned short* __restrict__ xh, const unsigned short* __restrict__ xl,
    const unsigned* __restrict__ Mtpk, const float* __restrict__ wv,
    float* __restrict__ partL, float* __restrict__ partA)
{
    __shared__ __align__(16) unsigned char Kt[2][GSTEP * 128];   // 2 x 8 KB
    __shared__ __align__(16) float wssh[GHALF];                  // 2 KB

    // XCD-chunked swizzle: 2048 blocks, 256 logical per XCD -> b in [4k,4k+4).
    const int bid = blockIdx.x;
    const int L = (bid & 7) * 256 + (bid >> 3);
    const int b   = L >> 6;
    const int r63 = L & 63;
    const int ftg = r63 >> 2;       // 0..15
    const int sp  = r63 & 3;        // 0..3

    const int tid  = threadIdx.x;
    const int lane = tid & 63;
    const int wid  = tid >> 6;
    const int col  = lane & 31;
    const int half = lane >> 5;
    const int fblk0  = ftg * 128 + wid * 32;
    const int gstart = sp * GHALF;
    const size_t bq = (size_t)b * FF;

    // ---- prologue: y[f][0..64) for f = fblk0+col, in-register ----
    f16x8 xhf[4], xlf[4];
    {
        const size_t xrow = (bq + fblk0 + col) * DPAD;
        #pragma unroll
        for (int ks = 0; ks < 4; ++ks) {
            xhf[ks] = *(const f16x8*)(xh + xrow + ks * 16 + half * 8);
            xlf[ks] = *(const f16x8*)(xl + xrow + ks * 16 + half * 8);
        }
    }

    unsigned pk[32];
    #pragma unroll
    for (int dt = 0; dt < 2; ++dt) {
        f16x8 mh[4], ml[4];
        #pragma unroll
        for (int ks = 0; ks < 4; ++ks) {
            const unsigned* mp = Mtpk + (dt * 32 + col) * 64 + ks * 16 + half * 8;
            unpack8(*(const uint4*)mp, *(const uint4*)(mp + 4), mh[ks], ml[ks]);
        }
        f32x16 acc;
        #pragma unroll
        for (int i = 0; i < 16; ++i) acc[i] = 0.f;
        #pragma unroll
        for (int ks = 0; ks < 4; ++ks) {
            acc = __builtin_amdgcn_mfma_f32_32x32x16_f16(mh[ks], xlf[ks], acc, 0, 0, 0);
            acc = __builtin_amdgcn_mfma_f32_32x32x16_f16(ml[ks], xhf[ks], acc, 0, 0, 0);
            acc = __builtin_amdgcn_mfma_f32_32x32x16_f16(mh[ks], xhf[ks], acc, 0, 0, 0);
        }
        #pragma unroll
        for (int r = 0; r < 16; ++r) pk[dt * 16 + r] = f16pack(acc[r]);
    }

    unsigned ot[32];
    #pragma unroll
    for (int j = 0; j < 32; ++j) ot[j] = __shfl_xor(pk[j], 32);

    f16x8 qhf[4], qlf[4];
    if (half == 0) build_frags<0>(pk, ot, qhf, qlf);
    else           build_frags<1>(pk, ot, qhf, qlf);

    // ---- main loop (round-10 proven structure) ----
    for (int i = tid; i < GHALF; i += 256) wssh[i] = wv[bq + gstart + i];

    // staging: 8 KB = 64 rows x 128 B; thread t writes 16B at D = t*16 (+4096),
    // LDS row = D>>7, slot s = (D>>4)&7; source chunk c = s ^ (row&7).
    int rowj[2], soj[2];
    #pragma unroll
    for (int j = 0; j < 2; ++j) {
        const int D = tid * 16 + j * 4096;
        rowj[j] = D >> 7;
        const int c = ((D >> 4) & 7) ^ (rowj[j] & 7);
        soj[j] = c * 8;                          // shorts
    }

    uint4 st[2];
    #pragma unroll
    for (int j = 0; j < 2; ++j)
        st[j] = *(const uint4*)(xh + (bq + gstart + rowj[j]) * DPAD + soj[j]);

    float lsum = 0.f, asum = 0.f;

    for (int t = 0; t < NSTEP; ++t) {
        const int buf = t & 1;
        *(uint4*)(&Kt[buf][tid * 16])        = st[0];
        *(uint4*)(&Kt[buf][tid * 16 + 4096]) = st[1];
        if (t + 1 < NSTEP) {
            const int gn = gstart + (t + 1) * GSTEP;
            #pragma unroll
            for (int j = 0; j < 2; ++j)
                st[j] = *(const uint4*)(xh + (bq + gn + rowj[j]) * DPAD + soj[j]);
        }
        __syncthreads();

        #pragma unroll
        for (int gsub = 0; gsub < 2; ++gsub) {
            const int rbase = gsub * 4096 + col * 128;
            const int a7 = col & 7;
            f32x16 acc;
            #pragma unroll
            for (int i = 0; i < 16; ++i) acc[i] = 0.f;
            #pragma unroll
            for (int ks = 0; ks < 4; ++ks) {
                const int c = ks * 2 + half;
                f16x8 ahf = *(const f16x8*)(&Kt[buf][rbase + ((c ^ a7) << 4)]);
                acc = __builtin_amdgcn_mfma_f32_32x32x16_f16(ahf, qlf[ks], acc, 0, 0, 0);
                acc = __builtin_amdgcn_mfma_f32_32x32x16_f16(ahf, qhf[ks], acc, 0, 0, 0);
            }
            // D row g = (reg&3) + 8*(reg>>2) + 4*half
            const float* wpb = wssh + t * GSTEP + gsub * 32 + 4 * half;
            #pragma unroll
            for (int q = 0; q < 4; ++q) {
                float4 w4 = *(const float4*)(wpb + q * 8);
                float p0 = exp2_fast(acc[q * 4 + 0]);
                float p1 = exp2_fast(acc[q * 4 + 1]);
                float p2 = exp2_fast(acc[q * 4 + 2]);
                float p3 = exp2_fast(acc[q * 4 + 3]);
                lsum += ((p0 + p1) + (p2 + p3));
                asum = fmaf(p0, w4.x, fmaf(p1, w4.y,
                       fmaf(p2, w4.z, fmaf(p3, w4.w, asum))));
            }
        }
    }

    lsum += __shfl_xor(lsum, 32);
    asum += __shfl_xor(asum, 32);
    if (half == 0) {
        size_t o = ((size_t)sp * BB + b) * FF + fblk0 + col;
        partL[o] = lsum;
        partA[o] = asum;
    }
}

// ---------------------------------------------------------------------------
// bn: combine split partials, BatchNorm over batch per channel f.
// ---------------------------------------------------------------------------
__global__ __launch_bounds__(64) void bn_kernel(
    const float* __restrict__ partL, const float* __restrict__ partA,
    const float* __restrict__ gamma, const float* __restrict__ beta,
    float* __restrict__ out)
{
    const int f = blockIdx.x * 64 + threadIdx.x;
    float v[BB];
    float mean = 0.f;
    #pragma unroll
    for (int b = 0; b < BB; ++b) {
        float l = 0.f, a = 0.f;
        #pragma unroll
        for (int s = 0; s < SPLIT; ++s) {
            l += partL[((size_t)s * BB + b) * FF + f];
            a += partA[((size_t)s * BB + b) * FF + f];
        }
        v[b] = a / l;
        mean += v[b];
    }
    mean *= (1.f / BB);
    float var = 0.f;
    #pragma unroll
    for (int b = 0; b < BB; ++b) {
        float d = v[b] - mean;
        var = fmaf(d, d, var);
    }
    var *= (1.f / BB);
    const float inv = rsqrtf(var + 1e-5f);
    const float g = gamma[f], be = beta[f];
    #pragma unroll
    for (int b = 0; b < BB; ++b)
        out[((size_t)b << 11) + f] = (v[b] - mean) * inv * g + be;
}

// ---------------------------------------------------------------------------
extern "C" void kernel_launch(void* const* d_in, const int* in_sizes, int n_in,
                              void* d_out, int out_size, void* d_ws, size_t ws_size,
                              hipStream_t stream)
{
    const float* x     = (const float*)d_in[0];
    const float* Wqkv  = (const float*)d_in[1];
    const float* Wout  = (const float*)d_in[2];
    // d_in[3] = b_out: cancels exactly under BatchNorm mean subtraction.
    const float* gamma = (const float*)d_in[4];
    const float* beta  = (const float*)d_in[5];

    char* wsb = (char*)d_ws;
    const size_t PANEL = (size_t)ROWS * DPAD * sizeof(unsigned short);  // 8 MB
    unsigned short* xh = (unsigned short*)(wsb);
    unsigned short* xl = (unsigned short*)(wsb + PANEL);
    float*          wv = (float*)(wsb + 2 * PANEL);                     // 256 KB
    unsigned*     Mtpk = (unsigned*)(wsb + 2 * PANEL + 262144);         // 16 KB
    float*           u = (float*)(wsb + 2 * PANEL + 262144 + 16384);
    float*       partL = (float*)(wsb + 2 * PANEL + 262144 + 17408);
    float*       partA = partL + (size_t)SPLIT * BB * FF;
    // total ~= 18.3 MiB

    prep_kernel<<<dim3(17), dim3(256), 0, stream>>>(Wqkv, Wout, Mtpk, u);

    xconv_kernel<<<dim3(ROWS / 128), dim3(256), 0, stream>>>(
        x, u, xh, xl, wv);

    attn_kernel<<<dim3(BB * 16 * SPLIT), dim3(256), 0, stream>>>(
        xh, xl, Mtpk, wv, partL, partA);

    bn_kernel<<<dim3(FF / 64), dim3(64), 0, stream>>>(
        partL, partA, gamma, beta, (float*)d_out);
}

// Round 12
// 88.459 us; speedup vs baseline: 1.0866x; 1.0866x over previous
//
#include <hip/hip_runtime.h>
#include <math.h>

// Problem constants: B=32, F=2048, hw=49, A=1.
#define BB    32
#define FF    2048
#define HW    49
#define ROWS  (BB * FF)
#define DPAD  64
#define SPLIT 4
#define GSTEP 64
#define GHALF (FF / SPLIT)               // 512
#define NSTEP (GHALF / GSTEP)            // 8

typedef float f32x16 __attribute__((ext_vector_type(16)));
typedef _Float16 f16x8 __attribute__((ext_vector_type(8)));
typedef short s16x8 __attribute__((ext_vector_type(8)));

// exp2 via the amdgcn builtin -> single v_exp_f32, compiler-managed hazards.
__device__ inline float exp2_fast(float x) {
    return __builtin_amdgcn_exp2f(x);
}

// fp32 -> fp16 hi + fp16 lo (RNE), packed (hi<<16)|lo. Combined rel err ~2^-22.
__device__ inline unsigned f16pack(float v) {
    _Float16 h = (_Float16)v;
    _Float16 l = (_Float16)(v - (float)h);
    unsigned hb = (unsigned)__builtin_bit_cast(unsigned short, h);
    unsigned lb = (unsigned)__builtin_bit_cast(unsigned short, l);
    return (hb << 16) | lb;
}

__device__ inline void unpack8(uint4 a, uint4 b, f16x8& h, f16x8& l) {
    unsigned w[8] = {a.x, a.y, a.z, a.w, b.x, b.y, b.z, b.w};
    s16x8 hs, ls;
    #pragma unroll
    for (int i = 0; i < 8; ++i) {
        hs[i] = (short)(w[i] >> 16);
        ls[i] = (short)(w[i] & 0xFFFFu);
    }
    h = __builtin_bit_cast(f16x8, hs);
    l = __builtin_bit_cast(f16x8, ls);
}

// ---------------------------------------------------------------------------
// prep: M[j,d] = sum_e Wq[e,j] Wk[e,d] * log2(e)/7 -> Mtpk[d][j] (fp16 hi/lo)
//       u[d]   = sum_e Wv[e,d] * Wout[e]
// ---------------------------------------------------------------------------
__global__ __launch_bounds__(256) void prep_kernel(
    const float* __restrict__ Wqkv, const float* __restrict__ Wout,
    unsigned* __restrict__ Mtpk, float* __restrict__ u)
{
    __shared__ float W2[98][52];
    const int tid = threadIdx.x;
    if (blockIdx.x < 16) {
        for (int i = tid; i < 98 * 52; i += 256) {
            int e = i / 52, j = i - e * 52;
            W2[e][j] = (j < HW) ? Wqkv[e * HW + j] : 0.f;
        }
        __syncthreads();
        const int d = blockIdx.x * 4 + (tid >> 6);
        const int j = tid & 63;
        float s = 0.f;
        if (d < HW && j < HW) {
            for (int e = 0; e < HW; ++e) s = fmaf(W2[e][j], W2[49 + e][d], s);
            s *= 0.2060992915555662f;      // log2(e) / 7
        }
        Mtpk[d * 64 + j] = f16pack(s);
    } else {
        if (tid < 64) {
            float s = 0.f;
            if (tid < HW)
                for (int e = 0; e < HW; ++e)
                    s = fmaf(Wqkv[(98 + e) * HW + tid], Wout[e], s);
            u[tid] = s;
        }
    }
}

// ---------------------------------------------------------------------------
// xconv: x fp32 -> fp16 hi/lo panels xh/xl [row][64] + wv = x.u.
// XCD-affinity swizzle: XCD k produces b in [4k,4k+4).
// ---------------------------------------------------------------------------
__global__ __launch_bounds__(256) void xconv_kernel(
    const float* __restrict__ x, const float* __restrict__ u,
    unsigned short* __restrict__ xh, unsigned short* __restrict__ xl,
    float* __restrict__ wv)
{
    __shared__ float xsh[128 * HW];
    __shared__ float ush[64];
    const int blk = (blockIdx.x & 7) * 64 + (blockIdx.x >> 3);   // affinity map
    const int tid = threadIdx.x, lane = tid & 63, wid = tid >> 6;
    const int col = lane & 31, half = lane >> 5;
    if (tid < 64) ush[tid] = u[tid];

    {
        const float* xb = x + (size_t)blk * 128 * HW;
        for (int i = tid; i < 128 * HW; i += 256) xsh[i] = xb[i];
    }
    __syncthreads();

    const int rloc = wid * 32 + col;
    const int row = blk * 128 + rloc;

    float wp = 0.f;
    #pragma unroll
    for (int ks = 0; ks < 4; ++ks) {
        s16x8 hs, ls;
        #pragma unroll
        for (int i = 0; i < 8; ++i) {
            int d = ks * 16 + half * 8 + i;
            float t = (d < HW) ? xsh[rloc * HW + d] : 0.f;
            wp = fmaf(t, ush[d], wp);
            _Float16 h = (_Float16)t;
            _Float16 l = (_Float16)(t - (float)h);
            hs[i] = __builtin_bit_cast(short, h);
            ls[i] = __builtin_bit_cast(short, l);
        }
        const size_t o = (size_t)row * DPAD + ks * 16 + half * 8;
        *(f16x8*)(xh + o) = __builtin_bit_cast(f16x8, hs);
        *(f16x8*)(xl + o) = __builtin_bit_cast(f16x8, ls);
    }
    wp += __shfl_xor(wp, 32);
    if (half == 0) wv[row] = wp;
}

// ---------------------------------------------------------------------------
// yfrag: y = x.M (3-MFMA fp16 hi/lo, full precision) -> y-hi fp16 panel
// yh[row][64]. Same affinity swizzle as xconv: reads xh/xl from the local
// XCD's L2, writes 1 MB/XCD -> whole pipeline stays L2-local.
// ---------------------------------------------------------------------------
__global__ __launch_bounds__(256) void yfrag_kernel(
    const unsigned short* __restrict__ xh, const unsigned short* __restrict__ xl,
    const unsigned* __restrict__ Mtpk, unsigned short* __restrict__ yh)
{
    const int blk = (blockIdx.x & 7) * 64 + (blockIdx.x >> 3);   // affinity map
    const int tid = threadIdx.x, lane = tid & 63, wid = tid >> 6;
    const int col = lane & 31, half = lane >> 5;
    const int r0 = blk * 128 + wid * 32;
    const int row = r0 + col;

    f16x8 ah[4], al[4];
    {
        const size_t xrow = (size_t)row * DPAD;
        #pragma unroll
        for (int ks = 0; ks < 4; ++ks) {
            ah[ks] = *(const f16x8*)(xh + xrow + ks * 16 + half * 8);
            al[ks] = *(const f16x8*)(xl + xrow + ks * 16 + half * 8);
        }
    }

    for (int dt = 0; dt < 2; ++dt) {
        f16x8 mh[4], ml[4];
        #pragma unroll
        for (int ks = 0; ks < 4; ++ks) {
            const unsigned* mp = Mtpk + (dt * 32 + col) * 64 + ks * 16 + half * 8;
            unpack8(*(const uint4*)mp, *(const uint4*)(mp + 4), mh[ks], ml[ks]);
        }
        f32x16 acc;
        #pragma unroll
        for (int i = 0; i < 16; ++i) acc[i] = 0.f;
        #pragma unroll
        for (int ks = 0; ks < 4; ++ks) {
            acc = __builtin_amdgcn_mfma_f32_32x32x16_f16(ah[ks], ml[ks], acc, 0, 0, 0);
            acc = __builtin_amdgcn_mfma_f32_32x32x16_f16(al[ks], mh[ks], acc, 0, 0, 0);
            acc = __builtin_amdgcn_mfma_f32_32x32x16_f16(ah[ks], mh[ks], acc, 0, 0, 0);
        }
        #pragma unroll
        for (int reg = 0; reg < 16; ++reg) {
            int drow = (reg & 3) + 8 * (reg >> 2) + 4 * half;
            _Float16 hv = (_Float16)acc[reg];
            yh[(size_t)(r0 + drow) * DPAD + dt * 32 + col] =
                __builtin_bit_cast(unsigned short, hv);
        }
    }
}

// ---------------------------------------------------------------------------
// attn: scores(log2) = yh . xh^T, 1 MFMA per ks (both hi-only), no-max
// softmax via v_exp_f32, scalar value w. 4 waves x 32 f-cols, GHALF=512
// g-rows, K-tile 64 rows double-buffered. VGPR<=64 -> 8 blocks/CU
// (launch_bounds(256,8)); grid 2048 = one fully-resident cohort. All panel
// traffic local-L2 (affinity).
// ---------------------------------------------------------------------------
__global__ __launch_bounds__(256, 8) void attn_kernel(
    const unsigned short* __restrict__ xh, const unsigned short* __restrict__ yh,
    const float* __restrict__ wv,
    float* __restrict__ partL, float* __restrict__ partA)
{
    __shared__ __align__(16) unsigned char Kt[2][GSTEP * 128];   // 2 x 8 KB
    __shared__ __align__(16) float wssh[GHALF];                  // 2 KB

    // XCD-chunked swizzle: 2048 blocks, 256 logical per XCD -> b in [4k,4k+4).
    const int bid = blockIdx.x;
    const int L = (bid & 7) * 256 + (bid >> 3);
    const int b   = L >> 6;
    const int r63 = L & 63;
    const int ftg = r63 >> 2;       // 0..15
    const int sp  = r63 & 3;        // 0..3

    const int tid  = threadIdx.x;
    const int lane = tid & 63;
    const int wid  = tid >> 6;
    const int col  = lane & 31;
    const int half = lane >> 5;
    const int fblk0  = ftg * 128 + wid * 32;
    const int gstart = sp * GHALF;
    const size_t bq = (size_t)b * FF;

    // hoist y-hi fragments (B operand, col = fblk0+col)
    f16x8 qhf[4];
    {
        const size_t yrow = (bq + fblk0 + col) * DPAD;
        #pragma unroll
        for (int ks = 0; ks < 4; ++ks)
            qhf[ks] = *(const f16x8*)(yh + yrow + ks * 16 + half * 8);
    }

    for (int i = tid; i < GHALF; i += 256) wssh[i] = wv[bq + gstart + i];

    // staging: 8 KB = 64 rows x 128 B; thread t writes 16B at D = t*16 (+4096),
    // LDS row = D>>7, slot s = (D>>4)&7; source chunk c = s ^ (row&7).
    int rowj[2], soj[2];
    #pragma unroll
    for (int j = 0; j < 2; ++j) {
        const int D = tid * 16 + j * 4096;
        rowj[j] = D >> 7;
        const int c = ((D >> 4) & 7) ^ (rowj[j] & 7);
        soj[j] = c * 8;                          // shorts
    }

    uint4 st[2];
    #pragma unroll
    for (int j = 0; j < 2; ++j)
        st[j] = *(const uint4*)(xh + (bq + gstart + rowj[j]) * DPAD + soj[j]);

    float lsum = 0.f, asum = 0.f;

    for (int t = 0; t < NSTEP; ++t) {
        const int buf = t & 1;
        *(uint4*)(&Kt[buf][tid * 16])        = st[0];
        *(uint4*)(&Kt[buf][tid * 16 + 4096]) = st[1];
        if (t + 1 < NSTEP) {
            const int gn = gstart + (t + 1) * GSTEP;
            #pragma unroll
            for (int j = 0; j < 2; ++j)
                st[j] = *(const uint4*)(xh + (bq + gn + rowj[j]) * DPAD + soj[j]);
        }
        __syncthreads();

        #pragma unroll
        for (int gsub = 0; gsub < 2; ++gsub) {
            const int rbase = gsub * 4096 + col * 128;
            const int a7 = col & 7;
            f32x16 acc;
            #pragma unroll
            for (int i = 0; i < 16; ++i) acc[i] = 0.f;
            #pragma unroll
            for (int ks = 0; ks < 4; ++ks) {
                const int c = ks * 2 + half;
                f16x8 ahf = *(const f16x8*)(&Kt[buf][rbase + ((c ^ a7) << 4)]);
                acc = __builtin_amdgcn_mfma_f32_32x32x16_f16(ahf, qhf[ks], acc, 0, 0, 0);
            }
            // D row g = (reg&3) + 8*(reg>>2) + 4*half
            const float* wpb = wssh + t * GSTEP + gsub * 32 + 4 * half;
            #pragma unroll
            for (int q = 0; q < 4; ++q) {
                float4 w4 = *(const float4*)(wpb + q * 8);
                float p0 = exp2_fast(acc[q * 4 + 0]);
                float p1 = exp2_fast(acc[q * 4 + 1]);
                float p2 = exp2_fast(acc[q * 4 + 2]);
                float p3 = exp2_fast(acc[q * 4 + 3]);
                lsum += ((p0 + p1) + (p2 + p3));
                asum = fmaf(p0, w4.x, fmaf(p1, w4.y,
                       fmaf(p2, w4.z, fmaf(p3, w4.w, asum))));
            }
        }
    }

    lsum += __shfl_xor(lsum, 32);
    asum += __shfl_xor(asum, 32);
    if (half == 0) {
        size_t o = ((size_t)sp * BB + b) * FF + fblk0 + col;
        partL[o] = lsum;
        partA[o] = asum;
    }
}

// ---------------------------------------------------------------------------
// bn: combine split partials, BatchNorm over batch per channel f.
// ---------------------------------------------------------------------------
__global__ __launch_bounds__(64) void bn_kernel(
    const float* __restrict__ partL, const float* __restrict__ partA,
    const float* __restrict__ gamma, const float* __restrict__ beta,
    float* __restrict__ out)
{
    const int f = blockIdx.x * 64 + threadIdx.x;
    float v[BB];
    float mean = 0.f;
    #pragma unroll
    for (int b = 0; b < BB; ++b) {
        float l = 0.f, a = 0.f;
        #pragma unroll
        for (int s = 0; s < SPLIT; ++s) {
            l += partL[((size_t)s * BB + b) * FF + f];
            a += partA[((size_t)s * BB + b) * FF + f];
        }
        v[b] = a / l;
        mean += v[b];
    }
    mean *= (1.f / BB);
    float var = 0.f;
    #pragma unroll
    for (int b = 0; b < BB; ++b) {
        float d = v[b] - mean;
        var = fmaf(d, d, var);
    }
    var *= (1.f / BB);
    const float inv = rsqrtf(var + 1e-5f);
    const float g = gamma[f], be = beta[f];
    #pragma unroll
    for (int b = 0; b < BB; ++b)
        out[((size_t)b << 11) + f] = (v[b] - mean) * inv * g + be;
}

// ---------------------------------------------------------------------------
extern "C" void kernel_launch(void* const* d_in, const int* in_sizes, int n_in,
                              void* d_out, int out_size, void* d_ws, size_t ws_size,
                              hipStream_t stream)
{
    const float* x     = (const float*)d_in[0];
    const float* Wqkv  = (const float*)d_in[1];
    const float* Wout  = (const float*)d_in[2];
    // d_in[3] = b_out: cancels exactly under BatchNorm mean subtraction.
    const float* gamma = (const float*)d_in[4];
    const float* beta  = (const float*)d_in[5];

    char* wsb = (char*)d_ws;
    const size_t PANEL = (size_t)ROWS * DPAD * sizeof(unsigned short);  // 8 MB
    unsigned short* xh = (unsigned short*)(wsb);
    unsigned short* xl = (unsigned short*)(wsb + PANEL);
    unsigned short* yh = (unsigned short*)(wsb + 2 * PANEL);
    float*          wv = (float*)(wsb + 3 * PANEL);                     // 256 KB
    unsigned*     Mtpk = (unsigned*)(wsb + 3 * PANEL + 262144);         // 16 KB
    float*           u = (float*)(wsb + 3 * PANEL + 262144 + 16384);
    float*       partL = (float*)(wsb + 3 * PANEL + 262144 + 17408);
    float*       partA = partL + (size_t)SPLIT * BB * FF;
    // total ~= 26.3 MiB

    prep_kernel<<<dim3(17), dim3(256), 0, stream>>>(Wqkv, Wout, Mtpk, u);

    xconv_kernel<<<dim3(ROWS / 128), dim3(256), 0, stream>>>(
        x, u, xh, xl, wv);

    yfrag_kernel<<<dim3(ROWS / 128), dim3(256), 0, stream>>>(
        xh, xl, Mtpk, yh);

    attn_kernel<<<dim3(BB * 16 * SPLIT), dim3(256), 0, stream>>>(
        xh, yh, wv, partL, partA);

    bn_kernel<<<dim3(FF / 64), dim3(64), 0, stream>>>(
        partL, partA, gamma, beta, (float*)d_out);
}

// Round 13
// 84.187 us; speedup vs baseline: 1.1418x; 1.0507x over previous
//
#include <hip/hip_runtime.h>
#include <math.h>

// Problem constants: B=32, F=2048, hw=49, A=1.
#define BB    32
#define FF    2048
#define HW    49
#define ROWS  (BB * FF)
#define DPAD  64
#define SPLIT 4
#define GSTEP 64
#define GHALF (FF / SPLIT)               // 512
#define NSTEP (GHALF / GSTEP)            // 8

typedef float f32x16 __attribute__((ext_vector_type(16)));
typedef _Float16 f16x8 __attribute__((ext_vector_type(8)));
typedef short s16x8 __attribute__((ext_vector_type(8)));

// exp2 via the amdgcn builtin -> single v_exp_f32, compiler-managed hazards.
__device__ inline float exp2_fast(float x) {
    return __builtin_amdgcn_exp2f(x);
}

// fp32 -> fp16 hi + fp16 lo (RNE), packed (hi<<16)|lo. Combined rel err ~2^-22.
__device__ inline unsigned f16pack(float v) {
    _Float16 h = (_Float16)v;
    _Float16 l = (_Float16)(v - (float)h);
    unsigned hb = (unsigned)__builtin_bit_cast(unsigned short, h);
    unsigned lb = (unsigned)__builtin_bit_cast(unsigned short, l);
    return (hb << 16) | lb;
}

__device__ inline void unpack8(uint4 a, uint4 b, f16x8& h, f16x8& l) {
    unsigned w[8] = {a.x, a.y, a.z, a.w, b.x, b.y, b.z, b.w};
    s16x8 hs, ls;
    #pragma unroll
    for (int i = 0; i < 8; ++i) {
        hs[i] = (short)(w[i] >> 16);
        ls[i] = (short)(w[i] & 0xFFFFu);
    }
    h = __builtin_bit_cast(f16x8, hs);
    l = __builtin_bit_cast(f16x8, ls);
}

// ---------------------------------------------------------------------------
// prep: M[j,d] = sum_e Wq[e,j] Wk[e,d] * log2(e)/7 -> Mtpk[d][j] (fp16 hi/lo)
//       u[d]   = sum_e Wv[e,d] * Wout[e]
// ---------------------------------------------------------------------------
__global__ __launch_bounds__(256) void prep_kernel(
    const float* __restrict__ Wqkv, const float* __restrict__ Wout,
    unsigned* __restrict__ Mtpk, float* __restrict__ u)
{
    __shared__ float W2[98][52];
    const int tid = threadIdx.x;
    if (blockIdx.x < 16) {
        for (int i = tid; i < 98 * 52; i += 256) {
            int e = i / 52, j = i - e * 52;
            W2[e][j] = (j < HW) ? Wqkv[e * HW + j] : 0.f;
        }
        __syncthreads();
        const int d = blockIdx.x * 4 + (tid >> 6);
        const int j = tid & 63;
        float s = 0.f;
        if (d < HW && j < HW) {
            for (int e = 0; e < HW; ++e) s = fmaf(W2[e][j], W2[49 + e][d], s);
            s *= 0.2060992915555662f;      // log2(e) / 7
        }
        Mtpk[d * 64 + j] = f16pack(s);
    } else {
        if (tid < 64) {
            float s = 0.f;
            if (tid < HW)
                for (int e = 0; e < HW; ++e)
                    s = fmaf(Wqkv[(98 + e) * HW + tid], Wout[e], s);
            u[tid] = s;
        }
    }
}

// ---------------------------------------------------------------------------
// xy (fused xconv+yfrag): load x via LDS bounce, build fp16 hi/lo x-frags
// in-register, write xh panel + wv = x.u, then y = x.M (3-MFMA hi/lo, full
// precision, xl never materialized) -> y-hi fp16 panel yh[row][64].
// XCD-affinity swizzle: XCD k produces b in [4k,4k+4) (what its attn reads).
// ---------------------------------------------------------------------------
__global__ __launch_bounds__(256) void xy_kernel(
    const float* __restrict__ x, const float* __restrict__ u,
    const unsigned* __restrict__ Mtpk,
    unsigned short* __restrict__ xh, unsigned short* __restrict__ yh,
    float* __restrict__ wv)
{
    __shared__ float xsh[128 * HW];
    __shared__ float ush[64];
    const int blk = (blockIdx.x & 7) * 64 + (blockIdx.x >> 3);   // affinity map
    const int tid = threadIdx.x, lane = tid & 63, wid = tid >> 6;
    const int col = lane & 31, half = lane >> 5;
    if (tid < 64) ush[tid] = u[tid];

    {
        const float* xb = x + (size_t)blk * 128 * HW;
        for (int i = tid; i < 128 * HW; i += 256) xsh[i] = xb[i];
    }
    __syncthreads();

    const int r0 = blk * 128 + wid * 32;
    const int rloc = wid * 32 + col;
    const int row = r0 + col;

    // x row -> hi/lo frags (in-register), xh panel write, wv partial
    f16x8 ah[4], al[4];
    float wp = 0.f;
    #pragma unroll
    for (int ks = 0; ks < 4; ++ks) {
        s16x8 hs, ls;
        #pragma unroll
        for (int i = 0; i < 8; ++i) {
            int d = ks * 16 + half * 8 + i;
            float t = (d < HW) ? xsh[rloc * HW + d] : 0.f;
            wp = fmaf(t, ush[d], wp);
            _Float16 h = (_Float16)t;
            _Float16 l = (_Float16)(t - (float)h);
            hs[i] = __builtin_bit_cast(short, h);
            ls[i] = __builtin_bit_cast(short, l);
        }
        ah[ks] = __builtin_bit_cast(f16x8, hs);
        al[ks] = __builtin_bit_cast(f16x8, ls);
        const size_t o = (size_t)row * DPAD + ks * 16 + half * 8;
        *(f16x8*)(xh + o) = ah[ks];
    }
    wp += __shfl_xor(wp, 32);
    if (half == 0) wv[row] = wp;

    // y = x.M for this wave's 32 rows (A = x-row frags, B = Mt-row frags)
    for (int dt = 0; dt < 2; ++dt) {
        f16x8 mh[4], ml[4];
        #pragma unroll
        for (int ks = 0; ks < 4; ++ks) {
            const unsigned* mp = Mtpk + (dt * 32 + col) * 64 + ks * 16 + half * 8;
            unpack8(*(const uint4*)mp, *(const uint4*)(mp + 4), mh[ks], ml[ks]);
        }
        f32x16 acc;
        #pragma unroll
        for (int i = 0; i < 16; ++i) acc[i] = 0.f;
        #pragma unroll
        for (int ks = 0; ks < 4; ++ks) {
            acc = __builtin_amdgcn_mfma_f32_32x32x16_f16(ah[ks], ml[ks], acc, 0, 0, 0);
            acc = __builtin_amdgcn_mfma_f32_32x32x16_f16(al[ks], mh[ks], acc, 0, 0, 0);
            acc = __builtin_amdgcn_mfma_f32_32x32x16_f16(ah[ks], mh[ks], acc, 0, 0, 0);
        }
        #pragma unroll
        for (int reg = 0; reg < 16; ++reg) {
            int drow = (reg & 3) + 8 * (reg >> 2) + 4 * half;
            _Float16 hv = (_Float16)acc[reg];
            yh[(size_t)(r0 + drow) * DPAD + dt * 32 + col] =
                __builtin_bit_cast(unsigned short, hv);
        }
    }
}

// ---------------------------------------------------------------------------
// attn: scores(log2) = yh . xh^T, 1 MFMA per ks (both hi-only), no-max
// softmax via v_exp_f32, scalar value w. 4 waves x 32 f-cols, GHALF=512
// g-rows, K-tile 64 rows double-buffered. launch_bounds(256,6): VGPR cap 85
// >= natural ~60 -> NO spill (round-12 lesson: (256,8) capped at 64,
// allocator hit 32, 45 MB scratch), 6 blocks/CU (LDS 6x18.4 = 110 KB).
// All panel traffic local-L2 (xy affinity).
// ---------------------------------------------------------------------------
__global__ __launch_bounds__(256, 6) void attn_kernel(
    const unsigned short* __restrict__ xh, const unsigned short* __restrict__ yh,
    const float* __restrict__ wv,
    float* __restrict__ partL, float* __restrict__ partA)
{
    __shared__ __align__(16) unsigned char Kt[2][GSTEP * 128];   // 2 x 8 KB
    __shared__ __align__(16) float wssh[GHALF];                  // 2 KB

    // XCD-chunked swizzle: 2048 blocks, 256 logical per XCD -> b in [4k,4k+4).
    const int bid = blockIdx.x;
    const int L = (bid & 7) * 256 + (bid >> 3);
    const int b   = L >> 6;
    const int r63 = L & 63;
    const int ftg = r63 >> 2;       // 0..15
    const int sp  = r63 & 3;        // 0..3

    const int tid  = threadIdx.x;
    const int lane = tid & 63;
    const int wid  = tid >> 6;
    const int col  = lane & 31;
    const int half = lane >> 5;
    const int fblk0  = ftg * 128 + wid * 32;
    const int gstart = sp * GHALF;
    const size_t bq = (size_t)b * FF;

    // hoist y-hi fragments (B operand, col = fblk0+col)
    f16x8 qhf[4];
    {
        const size_t yrow = (bq + fblk0 + col) * DPAD;
        #pragma unroll
        for (int ks = 0; ks < 4; ++ks)
            qhf[ks] = *(const f16x8*)(yh + yrow + ks * 16 + half * 8);
    }

    for (int i = tid; i < GHALF; i += 256) wssh[i] = wv[bq + gstart + i];

    // staging: 8 KB = 64 rows x 128 B; thread t writes 16B at D = t*16 (+4096),
    // LDS row = D>>7, slot s = (D>>4)&7; source chunk c = s ^ (row&7).
    int rowj[2], soj[2];
    #pragma unroll
    for (int j = 0; j < 2; ++j) {
        const int D = tid * 16 + j * 4096;
        rowj[j] = D >> 7;
        const int c = ((D >> 4) & 7) ^ (rowj[j] & 7);
        soj[j] = c * 8;                          // shorts
    }

    uint4 st[2];
    #pragma unroll
    for (int j = 0; j < 2; ++j)
        st[j] = *(const uint4*)(xh + (bq + gstart + rowj[j]) * DPAD + soj[j]);

    float lsum = 0.f, asum = 0.f;

    for (int t = 0; t < NSTEP; ++t) {
        const int buf = t & 1;
        *(uint4*)(&Kt[buf][tid * 16])        = st[0];
        *(uint4*)(&Kt[buf][tid * 16 + 4096]) = st[1];
        if (t + 1 < NSTEP) {
            const int gn = gstart + (t + 1) * GSTEP;
            #pragma unroll
            for (int j = 0; j < 2; ++j)
                st[j] = *(const uint4*)(xh + (bq + gn + rowj[j]) * DPAD + soj[j]);
        }
        __syncthreads();

        #pragma unroll
        for (int gsub = 0; gsub < 2; ++gsub) {
            const int rbase = gsub * 4096 + col * 128;
            const int a7 = col & 7;
            f32x16 acc;
            #pragma unroll
            for (int i = 0; i < 16; ++i) acc[i] = 0.f;
            #pragma unroll
            for (int ks = 0; ks < 4; ++ks) {
                const int c = ks * 2 + half;
                f16x8 ahf = *(const f16x8*)(&Kt[buf][rbase + ((c ^ a7) << 4)]);
                acc = __builtin_amdgcn_mfma_f32_32x32x16_f16(ahf, qhf[ks], acc, 0, 0, 0);
            }
            // D row g = (reg&3) + 8*(reg>>2) + 4*half
            const float* wpb = wssh + t * GSTEP + gsub * 32 + 4 * half;
            #pragma unroll
            for (int q = 0; q < 4; ++q) {
                float4 w4 = *(const float4*)(wpb + q * 8);
                float p0 = exp2_fast(acc[q * 4 + 0]);
                float p1 = exp2_fast(acc[q * 4 + 1]);
                float p2 = exp2_fast(acc[q * 4 + 2]);
                float p3 = exp2_fast(acc[q * 4 + 3]);
                lsum += ((p0 + p1) + (p2 + p3));
                asum = fmaf(p0, w4.x, fmaf(p1, w4.y,
                       fmaf(p2, w4.z, fmaf(p3, w4.w, asum))));
            }
        }
    }

    lsum += __shfl_xor(lsum, 32);
    asum += __shfl_xor(asum, 32);
    if (half == 0) {
        size_t o = ((size_t)sp * BB + b) * FF + fblk0 + col;
        partL[o] = lsum;
        partA[o] = asum;
    }
}

// ---------------------------------------------------------------------------
// bn: combine split partials, BatchNorm over batch per channel f.
// ---------------------------------------------------------------------------
__global__ __launch_bounds__(64) void bn_kernel(
    const float* __restrict__ partL, const float* __restrict__ partA,
    const float* __restrict__ gamma, const float* __restrict__ beta,
    float* __restrict__ out)
{
    const int f = blockIdx.x * 64 + threadIdx.x;
    float v[BB];
    float mean = 0.f;
    #pragma unroll
    for (int b = 0; b < BB; ++b) {
        float l = 0.f, a = 0.f;
        #pragma unroll
        for (int s = 0; s < SPLIT; ++s) {
            l += partL[((size_t)s * BB + b) * FF + f];
            a += partA[((size_t)s * BB + b) * FF + f];
        }
        v[b] = a / l;
        mean += v[b];
    }
    mean *= (1.f / BB);
    float var = 0.f;
    #pragma unroll
    for (int b = 0; b < BB; ++b) {
        float d = v[b] - mean;
        var = fmaf(d, d, var);
    }
    var *= (1.f / BB);
    const float inv = rsqrtf(var + 1e-5f);
    const float g = gamma[f], be = beta[f];
    #pragma unroll
    for (int b = 0; b < BB; ++b)
        out[((size_t)b << 11) + f] = (v[b] - mean) * inv * g + be;
}

// ---------------------------------------------------------------------------
extern "C" void kernel_launch(void* const* d_in, const int* in_sizes, int n_in,
                              void* d_out, int out_size, void* d_ws, size_t ws_size,
                              hipStream_t stream)
{
    const float* x     = (const float*)d_in[0];
    const float* Wqkv  = (const float*)d_in[1];
    const float* Wout  = (const float*)d_in[2];
    // d_in[3] = b_out: cancels exactly under BatchNorm mean subtraction.
    const float* gamma = (const float*)d_in[4];
    const float* beta  = (const float*)d_in[5];

    char* wsb = (char*)d_ws;
    const size_t PANEL = (size_t)ROWS * DPAD * sizeof(unsigned short);  // 8 MB
    unsigned short* xh = (unsigned short*)(wsb);
    unsigned short* yh = (unsigned short*)(wsb + PANEL);
    float*          wv = (float*)(wsb + 2 * PANEL);                     // 256 KB
    unsigned*     Mtpk = (unsigned*)(wsb + 2 * PANEL + 262144);         // 16 KB
    float*           u = (float*)(wsb + 2 * PANEL + 262144 + 16384);
    float*       partL = (float*)(wsb + 2 * PANEL + 262144 + 17408);
    float*       partA = partL + (size_t)SPLIT * BB * FF;
    // total ~= 18.3 MiB

    prep_kernel<<<dim3(17), dim3(256), 0, stream>>>(Wqkv, Wout, Mtpk, u);

    xy_kernel<<<dim3(ROWS / 128), dim3(256), 0, stream>>>(
        x, u, Mtpk, xh, yh, wv);

    attn_kernel<<<dim3(BB * 16 * SPLIT), dim3(256), 0, stream>>>(
        xh, yh, wv, partL, partA);

    bn_kernel<<<dim3(FF / 64), dim3(64), 0, stream>>>(
        partL, partA, gamma, beta, (float*)d_out);
}